// Round 3
// baseline (396.350 us; speedup 1.0000x reference)
//
#include <hip/hip_runtime.h>
#include <hip/hip_bf16.h>

typedef __attribute__((ext_vector_type(8))) short bf16x8;
typedef __attribute__((ext_vector_type(4))) float f32x4;

#define K_DIM 64

// ---------------- prep: one wave per row ----------------
// Split f32 row into bf16 hi/lo planes, compute row norm (exact fp32),
// and (for centres) inv_sigma2 = exp(-2*log_sigmas).
__global__ __launch_bounds__(256) void rbf_prep(
    const float* __restrict__ src, int rows,
    __hip_bfloat16* __restrict__ hi, __hip_bfloat16* __restrict__ lo,
    float* __restrict__ norms,
    const float* __restrict__ log_sigmas, float* __restrict__ inv_sigma2)
{
    int row  = blockIdx.x * 4 + (threadIdx.x >> 6);
    int lane = threadIdx.x & 63;
    if (row >= rows) return;

    float v = src[(size_t)row * K_DIM + lane];
    __hip_bfloat16 h = __float2bfloat16(v);
    float hf = __bfloat162float(h);
    __hip_bfloat16 l = __float2bfloat16(v - hf);
    hi[(size_t)row * K_DIM + lane] = h;
    lo[(size_t)row * K_DIM + lane] = l;

    float s = v * v;
    #pragma unroll
    for (int off = 32; off > 0; off >>= 1) s += __shfl_down(s, off, 64);
    if (lane == 0) {
        norms[row] = s;
        if (inv_sigma2) inv_sigma2[row] = __expf(-2.0f * log_sigmas[row]);
    }
}

// ---------------- main: block 64x64, 4 waves, 16x64 strip/wave ----------------
// Split-bf16 MFMA: dot = ahi*bhi + ahi*blo + alo*bhi (lo*lo dropped).
// Fragment layouts (measured m89/m91):
//   A: m = lane&15, k = (lane>>4)*8 + j
//   B: n = lane&15, k = (lane>>4)*8 + j
//   D: col = lane&15, row = (lane>>4)*4 + reg
__global__ __launch_bounds__(256) void rbf_main(
    const __hip_bfloat16* __restrict__ xhi, const __hip_bfloat16* __restrict__ xlo,
    const __hip_bfloat16* __restrict__ chi, const __hip_bfloat16* __restrict__ clo,
    const float* __restrict__ nx, const float* __restrict__ nc,
    const float* __restrict__ inv_sigma2,
    float* __restrict__ out, int N)
{
    const int wave = threadIdx.x >> 6;
    const int lane = threadIdx.x & 63;
    const int quad = lane >> 4;
    const int l16  = lane & 15;

    const int m_base = (blockIdx.y << 6) + (wave << 4);
    const int n_base = blockIdx.x << 6;

    const int am = m_base + l16;
    const bf16x8 ahi0 = *(const bf16x8*)(xhi + (size_t)am * K_DIM +      quad * 8);
    const bf16x8 ahi1 = *(const bf16x8*)(xhi + (size_t)am * K_DIM + 32 + quad * 8);
    const bf16x8 alo0 = *(const bf16x8*)(xlo + (size_t)am * K_DIM +      quad * 8);
    const bf16x8 alo1 = *(const bf16x8*)(xlo + (size_t)am * K_DIM + 32 + quad * 8);

    const f32x4 nx4 = *(const f32x4*)(nx + m_base + quad * 4);

    #pragma unroll
    for (int nt = 0; nt < 4; ++nt) {
        const int n = n_base + nt * 16 + l16;
        const bf16x8 bhi0 = *(const bf16x8*)(chi + (size_t)n * K_DIM +      quad * 8);
        const bf16x8 bhi1 = *(const bf16x8*)(chi + (size_t)n * K_DIM + 32 + quad * 8);
        const bf16x8 blo0 = *(const bf16x8*)(clo + (size_t)n * K_DIM +      quad * 8);
        const bf16x8 blo1 = *(const bf16x8*)(clo + (size_t)n * K_DIM + 32 + quad * 8);

        f32x4 acc = {0.f, 0.f, 0.f, 0.f};
        acc = __builtin_amdgcn_mfma_f32_16x16x32_bf16(ahi0, bhi0, acc, 0, 0, 0);
        acc = __builtin_amdgcn_mfma_f32_16x16x32_bf16(ahi1, bhi1, acc, 0, 0, 0);
        acc = __builtin_amdgcn_mfma_f32_16x16x32_bf16(ahi0, blo0, acc, 0, 0, 0);
        acc = __builtin_amdgcn_mfma_f32_16x16x32_bf16(ahi1, blo1, acc, 0, 0, 0);
        acc = __builtin_amdgcn_mfma_f32_16x16x32_bf16(alo0, bhi0, acc, 0, 0, 0);
        acc = __builtin_amdgcn_mfma_f32_16x16x32_bf16(alo1, bhi1, acc, 0, 0, 0);

        const float ncv  = nc[n];
        const float invv = inv_sigma2[n];
        #pragma unroll
        for (int r = 0; r < 4; ++r) {
            const int row = m_base + quad * 4 + r;
            float sq = fmaxf(nx4[r] + ncv - 2.0f * acc[r], 0.f);
            out[(size_t)row * N + n] = __expf(-sq * invv);
        }
    }
}

// ---------------- fallback: fully fused (R2's passing kernel) ----------------
__device__ __forceinline__ void split8(const float* __restrict__ p,
                                       bf16x8& hi, bf16x8& lo, float& ss) {
    #pragma unroll
    for (int j = 0; j < 8; ++j) {
        float v = p[j];
        ss = fmaf(v, v, ss);
        __hip_bfloat16 h = __float2bfloat16(v);
        float hf = __bfloat162float(h);
        __hip_bfloat16 l = __float2bfloat16(v - hf);
        hi[j] = *reinterpret_cast<const short*>(&h);
        lo[j] = *reinterpret_cast<const short*>(&l);
    }
}

__global__ __launch_bounds__(256) void rbf_fused(
    const float* __restrict__ x, const float* __restrict__ c,
    const float* __restrict__ ls, float* __restrict__ out, int N)
{
    const int wave = threadIdx.x >> 6;
    const int lane = threadIdx.x & 63;
    const int quad = lane >> 4;
    const int l16  = lane & 15;

    const int m_base = (blockIdx.y << 6) + (wave << 4);
    const int n_base = blockIdx.x << 6;

    const int am = m_base + l16;
    const float* xp = x + (size_t)am * K_DIM;
    bf16x8 ahi0, alo0, ahi1, alo1;
    float ssx = 0.f;
    split8(xp + quad * 8,      ahi0, alo0, ssx);
    split8(xp + 32 + quad * 8, ahi1, alo1, ssx);
    ssx += __shfl_xor(ssx, 16, 64);
    ssx += __shfl_xor(ssx, 32, 64);
    float nxr[4];
    #pragma unroll
    for (int r = 0; r < 4; ++r) nxr[r] = __shfl(ssx, quad * 4 + r, 64);

    #pragma unroll
    for (int nt = 0; nt < 4; ++nt) {
        const int n = n_base + nt * 16 + l16;
        const float* cp = c + (size_t)n * K_DIM;
        bf16x8 bhi0, blo0, bhi1, blo1;
        float ssc = 0.f;
        split8(cp + quad * 8,      bhi0, blo0, ssc);
        split8(cp + 32 + quad * 8, bhi1, blo1, ssc);
        ssc += __shfl_xor(ssc, 16, 64);
        ssc += __shfl_xor(ssc, 32, 64);

        f32x4 acc = {0.f, 0.f, 0.f, 0.f};
        acc = __builtin_amdgcn_mfma_f32_16x16x32_bf16(ahi0, bhi0, acc, 0, 0, 0);
        acc = __builtin_amdgcn_mfma_f32_16x16x32_bf16(ahi1, bhi1, acc, 0, 0, 0);
        acc = __builtin_amdgcn_mfma_f32_16x16x32_bf16(ahi0, blo0, acc, 0, 0, 0);
        acc = __builtin_amdgcn_mfma_f32_16x16x32_bf16(ahi1, blo1, acc, 0, 0, 0);
        acc = __builtin_amdgcn_mfma_f32_16x16x32_bf16(alo0, bhi0, acc, 0, 0, 0);
        acc = __builtin_amdgcn_mfma_f32_16x16x32_bf16(alo1, bhi1, acc, 0, 0, 0);

        const float invv = __expf(-2.0f * ls[n]);
        #pragma unroll
        for (int r = 0; r < 4; ++r) {
            const int row = m_base + quad * 4 + r;
            float sq = fmaxf(nxr[r] + ssc - 2.0f * acc[r], 0.f);
            out[(size_t)row * N + n] = __expf(-sq * invv);
        }
    }
}

extern "C" void kernel_launch(void* const* d_in, const int* in_sizes, int n_in,
                              void* d_out, int out_size, void* d_ws, size_t ws_size,
                              hipStream_t stream) {
    const float* x  = (const float*)d_in[0];   // [M,64]
    const float* c  = (const float*)d_in[1];   // [N,64]
    const float* ls = (const float*)d_in[2];   // [N]
    float* out = (float*)d_out;                // [M,N]

    const int M = in_sizes[0] / K_DIM;   // 16384
    const int N = in_sizes[2];           // 4096

    // Workspace layout
    size_t off = 0;
    auto place = [&](size_t bytes) { size_t p = off; off += (bytes + 255) & ~(size_t)255; return p; };
    size_t o_xhi = place((size_t)M * K_DIM * 2);
    size_t o_xlo = place((size_t)M * K_DIM * 2);
    size_t o_chi = place((size_t)N * K_DIM * 2);
    size_t o_clo = place((size_t)N * K_DIM * 2);
    size_t o_nx  = place((size_t)M * 4);
    size_t o_nc  = place((size_t)N * 4);
    size_t o_inv = place((size_t)N * 4);

    if (ws_size >= off) {
        char* ws = (char*)d_ws;
        __hip_bfloat16* xhi = (__hip_bfloat16*)(ws + o_xhi);
        __hip_bfloat16* xlo = (__hip_bfloat16*)(ws + o_xlo);
        __hip_bfloat16* chi = (__hip_bfloat16*)(ws + o_chi);
        __hip_bfloat16* clo = (__hip_bfloat16*)(ws + o_clo);
        float* nx  = (float*)(ws + o_nx);
        float* nc  = (float*)(ws + o_nc);
        float* inv = (float*)(ws + o_inv);

        rbf_prep<<<dim3((M + 3) / 4), 256, 0, stream>>>(x, M, xhi, xlo, nx, nullptr, nullptr);
        rbf_prep<<<dim3((N + 3) / 4), 256, 0, stream>>>(c, N, chi, clo, nc, ls, inv);
        rbf_main<<<dim3(N / 64, M / 64), 256, 0, stream>>>(xhi, xlo, chi, clo, nx, nc, inv, out, N);
    } else {
        rbf_fused<<<dim3(N / 64, M / 64), 256, 0, stream>>>(x, c, ls, out, N);
    }
}